// Round 10
// baseline (137.445 us; speedup 1.0000x reference)
//
#include <hip/hip_runtime.h>

#define NN 10000
#define EE 160000
#define DD 512
#define CAP 128   // bucket capacity; deg ~ Poisson(16), P(>=128) ~ 0 (writes clamped)

typedef float floatx4 __attribute__((ext_vector_type(4)));
typedef short short8 __attribute__((ext_vector_type(8)));

#define AS3(p) ((__attribute__((address_space(3))) void*)(p))
#define AS1(p) ((const __attribute__((address_space(1))) void*)(p))

static __device__ __forceinline__ unsigned short f2bf(float f) {
    unsigned int u = __float_as_uint(f);
    unsigned int r = (u + 0x7fffu + ((u >> 16) & 1u)) >> 16;
    return (unsigned short)r;
}
static __device__ __forceinline__ unsigned int pack2bf(float a, float b) {
    return (unsigned int)f2bf(a) | ((unsigned int)f2bf(b) << 16);
}
static __device__ __forceinline__ float bflo(unsigned int u) {
    return __uint_as_float(u << 16);
}
static __device__ __forceinline__ float bfhi(unsigned int u) {
    return __uint_as_float(u & 0xffff0000u);
}

// ---------------- prep: W->W^T bf16 (LDS-tiled) | deg accum + bucket ----------------

#define WT_BLOCKS 256
#define EDGE_BLOCKS 625

__global__ __launch_bounds__(256) void k_prep(const float* __restrict__ W,
                                              const int* __restrict__ row,
                                              const int* __restrict__ col,
                                              const float* __restrict__ ew,
                                              unsigned short* __restrict__ wtb,
                                              float* __restrict__ deg,
                                              int* __restrict__ cursor,
                                              uint2* __restrict__ erw) {
    const int b = blockIdx.x;
    const int tid = threadIdx.x;
    if (b < WT_BLOCKS) {
        __shared__ float T[32][33];
        int bi = b & 15;          // k-tile
        int bj = b >> 4;          // n-tile
        int r0 = tid >> 5;        // 0..7
        int cc = tid & 31;
        #pragma unroll
        for (int k = 0; k < 4; k++) {
            int r = r0 + k * 8;
            T[r][cc] = W[(size_t)(bi * 32 + r) * DD + bj * 32 + cc];
        }
        __syncthreads();
        #pragma unroll
        for (int k = 0; k < 4; k++) {
            int r = r0 + k * 8;
            wtb[(size_t)(bj * 32 + r) * DD + bi * 32 + cc] = f2bf(T[cc][r]);   // wtb[n][k]=W[k][n]
        }
    } else {
        int e = (b - WT_BLOCKS) * 256 + tid;   // exactly covers EE
        int r = row[e];
        int t = col[e];
        float w = ew[e];
        atomicAdd(&deg[t], w);
        int p = atomicAdd(&cursor[t], 1);
        if (p < CAP) erw[t * CAP + p] = make_uint2((unsigned int)r, __float_as_uint(w));
    }
}

// ---------------- MFMA GEMM: hb = bf16( (x @ wtb^T) * dinv[row] ), 32x512 tile ----------------
// Full-N blocks: x read exactly once (inline fp32->bf16 A-staging), B via global_load_lds
// (wtb = 0.5 MB, L2-resident re-reads). Grid 313 blocks x 256 thr; LDS 34 KB.

__global__ __launch_bounds__(256) void k_gemm_mfma(const float* __restrict__ x,
                                                   const unsigned short* __restrict__ wtb,
                                                   const float* __restrict__ deg,
                                                   unsigned short* __restrict__ hb) {
    __shared__ unsigned short As[32 * 32];     // 2 KB
    __shared__ unsigned short Bs[512 * 32];    // 32 KB

    const int tid = threadIdx.x;
    const int wave = tid >> 6;
    const int lane = tid & 63;

    const int bm = blockIdx.x * 32;
    const int wn = wave * 128;               // wave's 128-col slice

    const int fm = lane & 15;
    const int kb = (lane >> 4) * 8;

    floatx4 acc[2][8];
    #pragma unroll
    for (int i = 0; i < 2; i++)
        #pragma unroll
        for (int j = 0; j < 8; j++)
            acc[i][j] = (floatx4){0.f, 0.f, 0.f, 0.f};

    // A-staging: thread -> (row = tid>>3, 4 floats at (tid&7)*4)
    const int ar = tid >> 3;                 // 0..31
    const int acg = (tid & 7) * 4;           // 0,4,..,28
    int agr = bm + ar; if (agr > NN - 1) agr = NN - 1;     // clamp (stores guarded)
    const float* asrc = x + (size_t)agr * DD + acg;

    // B-staging (global_load_lds): wave stages rows [wave*128, wave*128+128)
    const int srow = lane >> 2;              // 0..15
    const int scol = (lane & 3) * 8;         // 0,8,16,24

    for (int k0 = 0; k0 < DD; k0 += 32) {
        // B: 8 chunks of 16 rows per wave
        #pragma unroll
        for (int cc = 0; cc < 8; cc++) {
            int nr = wave * 128 + cc * 16 + srow;
            __builtin_amdgcn_global_load_lds(AS1(wtb + (size_t)nr * DD + k0 + scol),
                                             AS3(&Bs[(wave * 128 + cc * 16) * 32]), 16, 0, 0);
        }
        // A: fp32 load + convert + ds_write (1 float4/thread)
        {
            float4 v = *(const float4*)(asrc + k0);
            *(uint2*)&As[ar * 32 + acg] = make_uint2(pack2bf(v.x, v.y), pack2bf(v.z, v.w));
        }
        __syncthreads();

        short8 af[2], bfr[8];
        #pragma unroll
        for (int mi = 0; mi < 2; mi++)
            af[mi] = *(const short8*)&As[(mi * 16 + fm) * 32 + kb];
        #pragma unroll
        for (int ni = 0; ni < 8; ni++)
            bfr[ni] = *(const short8*)&Bs[(wn + ni * 16 + fm) * 32 + kb];

        #pragma unroll
        for (int mi = 0; mi < 2; mi++)
            #pragma unroll
            for (int ni = 0; ni < 8; ni++)
                acc[mi][ni] = __builtin_amdgcn_mfma_f32_16x16x32_bf16(af[mi], bfr[ni], acc[mi][ni], 0, 0, 0);

        __syncthreads();
    }

    // fold dinv[row] into stored hb
    float dv[2][4];
    #pragma unroll
    for (int mi = 0; mi < 2; mi++) {
        int rbase = bm + mi * 16 + (lane >> 4) * 4;
        #pragma unroll
        for (int j = 0; j < 4; j++) {
            int rg = rbase + j; if (rg > NN - 1) rg = NN - 1;
            dv[mi][j] = rsqrtf(deg[rg] + 1.0f);
        }
    }

    #pragma unroll
    for (int mi = 0; mi < 2; mi++) {
        #pragma unroll
        for (int ni = 0; ni < 8; ni++) {
            int colg = wn + ni * 16 + (lane & 15);
            int rbase = bm + mi * 16 + (lane >> 4) * 4;
            #pragma unroll
            for (int j = 0; j < 4; j++) {
                int rg = rbase + j;
                if (rg < NN) hb[(size_t)rg * DD + colg] = f2bf(acc[mi][ni][j] * dv[mi][j]);
            }
        }
    }
}

// ---------------- aggregate: column-QUARTER split, XCD-partitioned ----------------

#define EDGE_FMA1(P, W) \
    acc0 += bflo(P) * W; acc1 += bfhi(P) * W;

__global__ __launch_bounds__(256, 8) void k_aggregate(const int* __restrict__ cursor,
                                                      const uint2* __restrict__ erw,
                                                      const unsigned short* __restrict__ hb,
                                                      const float* __restrict__ deg,
                                                      const float* __restrict__ bias,
                                                      float* __restrict__ out) {
    const int w = threadIdx.x >> 6;            // wave 0..3 -> node within group
    const int t = threadIdx.x & 63;
    const int bid = blockIdx.x;                // 0..9999
    const int quarter = bid & 3;
    const int i = (bid >> 2) * 4 + w;          // node (NN % 4 == 0)
    const int c = quarter * 128 + t * 2;       // bf16 col index, 2 cols/lane

    __shared__ int   s_r[4][CAP];
    __shared__ float s_w[4][CAP];

    int cnt = cursor[i];
    if (cnt > CAP) cnt = CAP;
    const uint2* bkt = erw + (size_t)i * CAP;
    if (t < cnt)      { uint2 p = bkt[t];      s_r[w][t]      = (int)p.x; s_w[w][t]      = __uint_as_float(p.y); }
    if (t + 64 < cnt) { uint2 p = bkt[t + 64]; s_r[w][t + 64] = (int)p.x; s_w[w][t + 64] = __uint_as_float(p.y); }

    // hoist self-row + bias
    float dv = rsqrtf(deg[i] + 1.0f);
    unsigned int hv = *(const unsigned int*)&hb[(size_t)i * DD + c];
    float2 bv = *(const float2*)&bias[c];

    __syncthreads();

    float acc0 = 0.f, acc1 = 0.f;

    int j = 0;
    for (; j + 8 <= cnt; j += 8) {
        unsigned int p0 = *(const unsigned int*)&hb[(size_t)s_r[w][j    ] * DD + c];
        unsigned int p1 = *(const unsigned int*)&hb[(size_t)s_r[w][j + 1] * DD + c];
        unsigned int p2 = *(const unsigned int*)&hb[(size_t)s_r[w][j + 2] * DD + c];
        unsigned int p3 = *(const unsigned int*)&hb[(size_t)s_r[w][j + 3] * DD + c];
        unsigned int p4 = *(const unsigned int*)&hb[(size_t)s_r[w][j + 4] * DD + c];
        unsigned int p5 = *(const unsigned int*)&hb[(size_t)s_r[w][j + 5] * DD + c];
        unsigned int p6 = *(const unsigned int*)&hb[(size_t)s_r[w][j + 6] * DD + c];
        unsigned int p7 = *(const unsigned int*)&hb[(size_t)s_r[w][j + 7] * DD + c];
        float w0 = s_w[w][j],     w1 = s_w[w][j + 1], w2 = s_w[w][j + 2], w3 = s_w[w][j + 3];
        float w4 = s_w[w][j + 4], w5 = s_w[w][j + 5], w6 = s_w[w][j + 6], w7 = s_w[w][j + 7];
        EDGE_FMA1(p0, w0) EDGE_FMA1(p1, w1) EDGE_FMA1(p2, w2) EDGE_FMA1(p3, w3)
        EDGE_FMA1(p4, w4) EDGE_FMA1(p5, w5) EDGE_FMA1(p6, w6) EDGE_FMA1(p7, w7)
    }
    for (; j + 4 <= cnt; j += 4) {
        unsigned int p0 = *(const unsigned int*)&hb[(size_t)s_r[w][j    ] * DD + c];
        unsigned int p1 = *(const unsigned int*)&hb[(size_t)s_r[w][j + 1] * DD + c];
        unsigned int p2 = *(const unsigned int*)&hb[(size_t)s_r[w][j + 2] * DD + c];
        unsigned int p3 = *(const unsigned int*)&hb[(size_t)s_r[w][j + 3] * DD + c];
        float w0 = s_w[w][j], w1 = s_w[w][j + 1], w2 = s_w[w][j + 2], w3 = s_w[w][j + 3];
        EDGE_FMA1(p0, w0) EDGE_FMA1(p1, w1) EDGE_FMA1(p2, w2) EDGE_FMA1(p3, w3)
    }
    for (; j < cnt; j++) {
        unsigned int p0 = *(const unsigned int*)&hb[(size_t)s_r[w][j] * DD + c];
        float w0 = s_w[w][j];
        EDGE_FMA1(p0, w0)
    }

    float2 o;
    o.x = (acc0 + bflo(hv)) * dv + bv.x;
    o.y = (acc1 + bfhi(hv)) * dv + bv.y;
    *(float2*)&out[(size_t)i * DD + c] = o;
}

extern "C" void kernel_launch(void* const* d_in, const int* in_sizes, int n_in,
                              void* d_out, int out_size, void* d_ws, size_t ws_size,
                              hipStream_t stream) {
    const float* x  = (const float*)d_in[0];
    const int*   ei = (const int*)d_in[1];
    const float* ea = (const float*)d_in[2];
    const float* W  = (const float*)d_in[3];
    const float* b  = (const float*)d_in[4];
    float* out = (float*)d_out;

    char* ws = (char*)d_ws;
    unsigned short* hb   = (unsigned short*)ws;                 // 10,240,000 B
    unsigned short* wtb  = (unsigned short*)(ws + 10240000);    // 524,288 B
    float* deg    = (float*)(ws + 10764288);                    // 40,960 B
    int*   cursor = (int*)  (ws + 10805248);                    // 40,960 B
    uint2* erw    = (uint2*)(ws + 10846208);                    // 10,240,000 B

    const int* row = ei;
    const int* col = ei + EE;

    hipMemsetAsync(deg, 0, 81920, stream);   // deg + cursor (contiguous)

    k_prep<<<WT_BLOCKS + EDGE_BLOCKS, 256, 0, stream>>>(W, row, col, ea, wtb, deg, cursor, erw);

    k_gemm_mfma<<<(NN + 31) / 32, 256, 0, stream>>>(x, wtb, deg, hb);

    k_aggregate<<<NN, 256, 0, stream>>>(cursor, erw, hb, deg, b, out);
}

// Round 13
// 132.891 us; speedup vs baseline: 1.0343x; 1.0343x over previous
//
#include <hip/hip_runtime.h>

#define NN 10000
#define EE 160000
#define DD 512
#define CAP 128   // bucket capacity; deg ~ Poisson(16), P(>=128) ~ 0 (writes clamped)

typedef float floatx4 __attribute__((ext_vector_type(4)));
typedef short short8 __attribute__((ext_vector_type(8)));

#define AS3(p) ((__attribute__((address_space(3))) void*)(p))
#define AS1(p) ((const __attribute__((address_space(1))) void*)(p))

static __device__ __forceinline__ unsigned short f2bf(float f) {
    unsigned int u = __float_as_uint(f);
    unsigned int r = (u + 0x7fffu + ((u >> 16) & 1u)) >> 16;
    return (unsigned short)r;
}
static __device__ __forceinline__ float bflo(unsigned int u) {
    return __uint_as_float(u << 16);
}
static __device__ __forceinline__ float bfhi(unsigned int u) {
    return __uint_as_float(u & 0xffff0000u);
}

// ---------------- fused prep: x->bf16 | W->W^T bf16 (LDS-tiled) | deg accum + bucket ----------------

#define XB_BLOCKS 5000
#define WT_BLOCKS 256
#define EDGE_BLOCKS 625

__global__ __launch_bounds__(256) void k_prep(const float* __restrict__ x,
                                              const float* __restrict__ W,
                                              const int* __restrict__ row,
                                              const int* __restrict__ col,
                                              const float* __restrict__ ew,
                                              unsigned short* __restrict__ xb,
                                              unsigned short* __restrict__ wtb,
                                              float* __restrict__ deg,
                                              int* __restrict__ cursor,
                                              uint2* __restrict__ erw) {
    const int b = blockIdx.x;
    const int tid = threadIdx.x;
    if (b < XB_BLOCKS) {
        int gid = b * 256 + tid;                     // float4 group of x
        float4 v = *(const float4*)&x[(size_t)gid * 4];
        unsigned int p0 = (unsigned int)f2bf(v.x) | ((unsigned int)f2bf(v.y) << 16);
        unsigned int p1 = (unsigned int)f2bf(v.z) | ((unsigned int)f2bf(v.w) << 16);
        *(uint2*)&xb[(size_t)gid * 4] = make_uint2(p0, p1);
    } else if (b < XB_BLOCKS + WT_BLOCKS) {
        __shared__ float T[32][33];
        int idx = b - XB_BLOCKS;
        int bi = idx & 15;        // k-tile
        int bj = idx >> 4;        // n-tile
        int r0 = tid >> 5;        // 0..7
        int cc = tid & 31;
        #pragma unroll
        for (int k = 0; k < 4; k++) {
            int r = r0 + k * 8;
            T[r][cc] = W[(size_t)(bi * 32 + r) * DD + bj * 32 + cc];
        }
        __syncthreads();
        #pragma unroll
        for (int k = 0; k < 4; k++) {
            int r = r0 + k * 8;
            wtb[(size_t)(bj * 32 + r) * DD + bi * 32 + cc] = f2bf(T[cc][r]);   // wtb[n][k]=W[k][n]
        }
    } else {
        int e = (b - XB_BLOCKS - WT_BLOCKS) * 256 + tid;   // exactly covers EE
        int r = row[e];
        int t = col[e];
        float w = ew[e];
        atomicAdd(&deg[t], w);
        int p = atomicAdd(&cursor[t], 1);
        if (p < CAP) erw[t * CAP + p] = make_uint2((unsigned int)r, __float_as_uint(w));
    }
}

// ---------------- MFMA GEMM: hb = bf16( (xb @ wtb^T) * dinv[row] ), 64x128 tile ----------------

__global__ __launch_bounds__(256) void k_gemm_mfma(const unsigned short* __restrict__ xb,
                                                   const unsigned short* __restrict__ wtb,
                                                   const float* __restrict__ deg,
                                                   unsigned short* __restrict__ hb) {
    __shared__ unsigned short As[64 * 32];    // 4 KB
    __shared__ unsigned short Bs[128 * 32];   // 8 KB

    const int tid = threadIdx.x;
    const int wave = tid >> 6;
    const int lane = tid & 63;

    const int bm = blockIdx.x * 64;
    const int bn = blockIdx.y * 128;

    const int wm = (wave >> 1) * 32;   // 0 / 32
    const int wn = (wave & 1) * 64;    // 0 / 64

    const int fm = lane & 15;
    const int kb = (lane >> 4) * 8;

    floatx4 acc[2][4];
    #pragma unroll
    for (int i = 0; i < 2; i++)
        #pragma unroll
        for (int j = 0; j < 4; j++)
            acc[i][j] = (floatx4){0.f, 0.f, 0.f, 0.f};

    const int srow = lane >> 2;          // 0..15 within a 16-row chunk
    const int scol = (lane & 3) * 8;     // 0,8,16,24

    for (int k0 = 0; k0 < DD; k0 += 32) {
        // A: 64 rows, one chunk per wave
        {
            int r = wave * 16 + srow;
            int gr = bm + r; if (gr > NN - 1) gr = NN - 1;   // clamp (stores guarded)
            __builtin_amdgcn_global_load_lds(AS1(xb + (size_t)gr * DD + k0 + scol),
                                             AS3(&As[wave * 512]), 16, 0, 0);
        }
        // B: 128 rows, two chunks per wave
        #pragma unroll
        for (int cc = 0; cc < 2; cc++) {
            int c = wave + cc * 4;
            int nr = bn + c * 16 + srow;
            __builtin_amdgcn_global_load_lds(AS1(wtb + (size_t)nr * DD + k0 + scol),
                                             AS3(&Bs[c * 512]), 16, 0, 0);
        }
        __syncthreads();

        short8 af[2], bfr[4];
        #pragma unroll
        for (int mi = 0; mi < 2; mi++)
            af[mi] = *(const short8*)&As[(wm + mi * 16 + fm) * 32 + kb];
        #pragma unroll
        for (int ni = 0; ni < 4; ni++)
            bfr[ni] = *(const short8*)&Bs[(wn + ni * 16 + fm) * 32 + kb];

        #pragma unroll
        for (int mi = 0; mi < 2; mi++)
            #pragma unroll
            for (int ni = 0; ni < 4; ni++)
                acc[mi][ni] = __builtin_amdgcn_mfma_f32_16x16x32_bf16(af[mi], bfr[ni], acc[mi][ni], 0, 0, 0);

        __syncthreads();
    }

    // fold dinv[row] into stored hb
    float dv[2][4];
    #pragma unroll
    for (int mi = 0; mi < 2; mi++) {
        int rbase = bm + wm + mi * 16 + (lane >> 4) * 4;
        #pragma unroll
        for (int j = 0; j < 4; j++) {
            int rg = rbase + j; if (rg > NN - 1) rg = NN - 1;
            dv[mi][j] = rsqrtf(deg[rg] + 1.0f);
        }
    }

    #pragma unroll
    for (int mi = 0; mi < 2; mi++) {
        #pragma unroll
        for (int ni = 0; ni < 4; ni++) {
            int colg = bn + wn + ni * 16 + (lane & 15);
            int rbase = bm + wm + mi * 16 + (lane >> 4) * 4;
            #pragma unroll
            for (int j = 0; j < 4; j++) {
                int rg = rbase + j;
                if (rg < NN) hb[(size_t)rg * DD + colg] = f2bf(acc[mi][ni][j] * dv[mi][j]);
            }
        }
    }
}

// ---------------- aggregate: column-half split, XCD-parity placement ----------------
// Block bid (128 thr = 2 waves): half = bid&1, wave h handles node (bid>>1)*2 + h,
// columns [half*256, half*256+256). Under round-robin block->XCD dispatch, all
// half-0 blocks land on even XCDs -> per-XCD L2 working set of hb halves (10->5 MB).

#define EDGE_FMA2(P, W) \
    acc[0] += bflo(P.x) * W; acc[1] += bfhi(P.x) * W; \
    acc[2] += bflo(P.y) * W; acc[3] += bfhi(P.y) * W;

__global__ __launch_bounds__(128, 8) void k_aggregate(const int* __restrict__ cursor,
                                                      const uint2* __restrict__ erw,
                                                      const unsigned short* __restrict__ hb,
                                                      const float* __restrict__ deg,
                                                      const float* __restrict__ bias,
                                                      float* __restrict__ out) {
    const int h = threadIdx.x >> 6;
    const int t = threadIdx.x & 63;
    const int bid = blockIdx.x;                // 0..9999
    const int half = bid & 1;
    const int i = (bid >> 1) * 2 + h;          // node
    const int c = half * 256 + t * 4;          // bf16 col index, 4 cols/lane

    __shared__ int   s_r[2][CAP];
    __shared__ float s_w[2][CAP];

    int cnt = cursor[i];
    if (cnt > CAP) cnt = CAP;
    const uint2* bkt = erw + (size_t)i * CAP;
    if (t < cnt)      { uint2 p = bkt[t];      s_r[h][t]      = (int)p.x; s_w[h][t]      = __uint_as_float(p.y); }
    if (t + 64 < cnt) { uint2 p = bkt[t + 64]; s_r[h][t + 64] = (int)p.x; s_w[h][t + 64] = __uint_as_float(p.y); }

    // hoist self-row + bias
    float dv = rsqrtf(deg[i] + 1.0f);
    uint2 hv = *(const uint2*)&hb[(size_t)i * DD + c];
    float4 bv = *(const float4*)&bias[c];

    __syncthreads();

    float acc[4] = {0.f, 0.f, 0.f, 0.f};

    int j = 0;
    for (; j + 8 <= cnt; j += 8) {
        uint2 p0 = *(const uint2*)&hb[(size_t)s_r[h][j    ] * DD + c];
        uint2 p1 = *(const uint2*)&hb[(size_t)s_r[h][j + 1] * DD + c];
        uint2 p2 = *(const uint2*)&hb[(size_t)s_r[h][j + 2] * DD + c];
        uint2 p3 = *(const uint2*)&hb[(size_t)s_r[h][j + 3] * DD + c];
        uint2 p4 = *(const uint2*)&hb[(size_t)s_r[h][j + 4] * DD + c];
        uint2 p5 = *(const uint2*)&hb[(size_t)s_r[h][j + 5] * DD + c];
        uint2 p6 = *(const uint2*)&hb[(size_t)s_r[h][j + 6] * DD + c];
        uint2 p7 = *(const uint2*)&hb[(size_t)s_r[h][j + 7] * DD + c];
        float w0 = s_w[h][j],     w1 = s_w[h][j + 1], w2 = s_w[h][j + 2], w3 = s_w[h][j + 3];
        float w4 = s_w[h][j + 4], w5 = s_w[h][j + 5], w6 = s_w[h][j + 6], w7 = s_w[h][j + 7];
        EDGE_FMA2(p0, w0) EDGE_FMA2(p1, w1) EDGE_FMA2(p2, w2) EDGE_FMA2(p3, w3)
        EDGE_FMA2(p4, w4) EDGE_FMA2(p5, w5) EDGE_FMA2(p6, w6) EDGE_FMA2(p7, w7)
    }
    for (; j + 4 <= cnt; j += 4) {
        uint2 p0 = *(const uint2*)&hb[(size_t)s_r[h][j    ] * DD + c];
        uint2 p1 = *(const uint2*)&hb[(size_t)s_r[h][j + 1] * DD + c];
        uint2 p2 = *(const uint2*)&hb[(size_t)s_r[h][j + 2] * DD + c];
        uint2 p3 = *(const uint2*)&hb[(size_t)s_r[h][j + 3] * DD + c];
        float w0 = s_w[h][j], w1 = s_w[h][j + 1], w2 = s_w[h][j + 2], w3 = s_w[h][j + 3];
        EDGE_FMA2(p0, w0) EDGE_FMA2(p1, w1) EDGE_FMA2(p2, w2) EDGE_FMA2(p3, w3)
    }
    for (; j < cnt; j++) {
        uint2 p0 = *(const uint2*)&hb[(size_t)s_r[h][j] * DD + c];
        float w0 = s_w[h][j];
        EDGE_FMA2(p0, w0)
    }

    float2 o0, o1;
    o0.x = (acc[0] + bflo(hv.x)) * dv + bv.x;
    o0.y = (acc[1] + bfhi(hv.x)) * dv + bv.y;
    o1.x = (acc[2] + bflo(hv.y)) * dv + bv.z;
    o1.y = (acc[3] + bfhi(hv.y)) * dv + bv.w;
    *(float2*)&out[(size_t)i * DD + c] = o0;
    *(float2*)&out[(size_t)i * DD + c + 2] = o1;
}

extern "C" void kernel_launch(void* const* d_in, const int* in_sizes, int n_in,
                              void* d_out, int out_size, void* d_ws, size_t ws_size,
                              hipStream_t stream) {
    const float* x  = (const float*)d_in[0];
    const int*   ei = (const int*)d_in[1];
    const float* ea = (const float*)d_in[2];
    const float* W  = (const float*)d_in[3];
    const float* b  = (const float*)d_in[4];
    float* out = (float*)d_out;

    char* ws = (char*)d_ws;
    unsigned short* hb   = (unsigned short*)ws;                 // 10,240,000 B
    unsigned short* xb   = (unsigned short*)(ws + 10240000);    // 10,240,000 B
    unsigned short* wtb  = (unsigned short*)(ws + 20480000);    // 524,288 B
    float* deg    = (float*)(ws + 21004288);                    // 40,960 B
    int*   cursor = (int*)  (ws + 21045248);                    // 40,960 B
    uint2* erw    = (uint2*)(ws + 21086208);                    // 10,240,000 B

    const int* row = ei;
    const int* col = ei + EE;

    hipMemsetAsync(deg, 0, 81920, stream);   // deg + cursor (contiguous)

    k_prep<<<XB_BLOCKS + WT_BLOCKS + EDGE_BLOCKS, 256, 0, stream>>>(x, W, row, col, ea,
                                                                    xb, wtb, deg, cursor, erw);

    dim3 ggrid((NN + 63) / 64, DD / 128);
    k_gemm_mfma<<<ggrid, 256, 0, stream>>>(xb, wtb, deg, hb);

    k_aggregate<<<NN, 128, 0, stream>>>(cursor, erw, hb, deg, b, out);
}